// Round 4
// baseline (656.294 us; speedup 1.0000x reference)
//
#include <hip/hip_runtime.h>

typedef __attribute__((ext_vector_type(8))) short bf16x8;
typedef __attribute__((ext_vector_type(4))) float f32x4;

#define HP  72   // h-tile pitch (shorts): 144B rows, 16B-aligned chunks
#define PWS 72   // node-kernel staging pitch (unchanged from round 3)

__device__ __forceinline__ float silu_f(float v) {
    return v * (1.0f / (1.0f + __expf(-v)));
}

// split f32 into hi (bf16 truncation, exact residual) + lo (bf16 of residual)
__device__ __forceinline__ void split_bf(float f, short& h, short& l) {
    unsigned u = __float_as_uint(f);
    h = (short)(u >> 16);
    float res = f - __uint_as_float(u & 0xffff0000u);   // exact
    l = (short)(__float_as_uint(res) >> 16);
}

// two float4 -> one (hi,lo) bf16x8 fragment pair
__device__ __forceinline__ void cvt8(const float4& a, const float4& b,
                                     bf16x8& h, bf16x8& l) {
    short hh, ll;
    split_bf(a.x, hh, ll); h[0] = hh; l[0] = ll;
    split_bf(a.y, hh, ll); h[1] = hh; l[1] = ll;
    split_bf(a.z, hh, ll); h[2] = hh; l[2] = ll;
    split_bf(a.w, hh, ll); h[3] = hh; l[3] = ll;
    split_bf(b.x, hh, ll); h[4] = hh; l[4] = ll;
    split_bf(b.y, hh, ll); h[5] = hh; l[5] = ll;
    split_bf(b.z, hh, ll); h[6] = hh; l[6] = ll;
    split_bf(b.w, hh, ll); h[7] = hh; l[7] = ll;
}

// ---------------------------------------------------------------------------
// Weight pre-conversion: fp32 [K][64] -> hi/lo bf16 in B-fragment order:
//   out[((t*4+nf)*64 + lane)*8 + j] = W[t*32 + (lane>>4)*8 + j][nf*16 + (lane&15)]
// ---------------------------------------------------------------------------
struct WDesc { const float* W; short* hi; short* lo; int K; };
struct WPack { WDesc d[8]; };

__global__ __launch_bounds__(256) void conv_weights(WPack p) {
    WDesc wd = p.d[blockIdx.y];
    int total = wd.K * 64;
    int i = blockIdx.x * 256 + threadIdx.x;
    if (i >= total) return;
    int j  = i & 7;
    int l  = (i >> 3) & 63;
    int tn = i >> 9;                 // t*4 + nf
    int t  = tn >> 2, nf = tn & 3;
    int k  = t * 32 + (l >> 4) * 8 + j;
    int c  = nf * 16 + (l & 15);
    float f = wd.W[k * 64 + c];
    unsigned u = __float_as_uint(f);
    short h = (short)(u >> 16);
    float res = f - __uint_as_float(u & 0xffff0000u);
    unsigned ur = __float_as_uint(res);
    short lo16 = (short)((ur + 0x7fffu + ((ur >> 16) & 1u)) >> 16);  // RNE
    wd.hi[i] = h;
    wd.lo[i] = lo16;
}

// ---------------------------------------------------------------------------
// Edge kernel: 4 independent waves / block, wave owns 16 edges.
// Layer-1 A-fragments loaded DIRECTLY from global (12 float4 issued upfront,
// one memory round-trip), converted in-register. LDS only for the h transpose.
// ---------------------------------------------------------------------------
__global__ __launch_bounds__(256, 4) void gnn_edge_mfma(
    const float* __restrict__ x,
    const float* __restrict__ ea_in,
    float* __restrict__ ea_out,
    const int* __restrict__ src_idx,
    const int* __restrict__ dst_idx,
    const short* __restrict__ w1h, const short* __restrict__ w1l,
    const float* __restrict__ b1,
    const short* __restrict__ w2h, const short* __restrict__ w2l,
    const float* __restrict__ b2,
    float* __restrict__ agg, int E)
{
    __shared__ __align__(16) short h_hi[64][HP];
    __shared__ __align__(16) short h_lo[64][HP];

    const int t    = threadIdx.x;
    const int lane = t & 63;
    const int w    = t >> 6;
    const int col  = lane & 15;
    const int g    = lane >> 4;
    const int ko   = g * 8;
    const long base = (long)blockIdx.x * 64;

    long er = base + w * 16 + col;           // this lane's A-row (edge id)
    if (er >= E) er = E - 1;
    const int si = src_idx[er];
    const int di = dst_idx[er];
    const float* pe = ea_in + er * 64 + ko;
    const float* ps = x + (long)si * 64 + ko;
    const float* pd = x + (long)di * 64 + ko;

    // ---- issue all 12 layer-1 A loads (independent -> back-to-back) ----
    float4 v0  = *(const float4*)(pe);
    float4 v1  = *(const float4*)(pe + 4);
    float4 v2  = *(const float4*)(pe + 32);
    float4 v3  = *(const float4*)(pe + 36);
    float4 v4  = *(const float4*)(ps);
    float4 v5  = *(const float4*)(ps + 4);
    float4 v6  = *(const float4*)(ps + 32);
    float4 v7  = *(const float4*)(ps + 36);
    float4 v8  = *(const float4*)(pd);
    float4 v9  = *(const float4*)(pd + 4);
    float4 v10 = *(const float4*)(pd + 32);
    float4 v11 = *(const float4*)(pd + 36);

    f32x4 acc[4];
#pragma unroll
    for (int nf = 0; nf < 4; ++nf) {
        float bv = b1[nf * 16 + col];
        acc[nf] = (f32x4){bv, bv, bv, bv};
    }

#define SIXTH(m, A, B)                                                          \
    {                                                                           \
        bf16x8 ah, al;                                                          \
        cvt8(A, B, ah, al);                                                     \
        _Pragma("unroll")                                                       \
        for (int nf = 0; nf < 4; ++nf) {                                        \
            bf16x8 bh = *(const bf16x8*)(w1h + (size_t)(((m)*4+nf)*64+lane)*8); \
            bf16x8 bl = *(const bf16x8*)(w1l + (size_t)(((m)*4+nf)*64+lane)*8); \
            acc[nf] = __builtin_amdgcn_mfma_f32_16x16x32_bf16(ah, bh, acc[nf], 0, 0, 0); \
            acc[nf] = __builtin_amdgcn_mfma_f32_16x16x32_bf16(ah, bl, acc[nf], 0, 0, 0); \
            acc[nf] = __builtin_amdgcn_mfma_f32_16x16x32_bf16(al, bh, acc[nf], 0, 0, 0); \
        }                                                                       \
    }

    SIXTH(0, v0, v1)  SIXTH(1, v2, v3)     // edge_attr  (k 0..63)
    SIXTH(2, v4, v5)  SIXTH(3, v6, v7)     // x[src]     (k 64..127)
    SIXTH(4, v8, v9)  SIXTH(5, v10, v11)   // x[dst]     (k 128..191)
#undef SIXTH

    // ---- silu -> h staged into the wave's own 16 LDS rows (C-frag layout) ----
#pragma unroll
    for (int nf = 0; nf < 4; ++nf)
#pragma unroll
        for (int rg = 0; rg < 4; ++rg) {
            int row = w * 16 + g * 4 + rg;
            short hh, hl;
            split_bf(silu_f(acc[nf][rg]), hh, hl);
            h_hi[row][nf * 16 + col] = hh;
            h_lo[row][nf * 16 + col] = hl;
        }

    // ---- layer-2 GEMM (K=64) ----
    f32x4 out[4];
#pragma unroll
    for (int nf = 0; nf < 4; ++nf) {
        float bv = b2[nf * 16 + col];
        out[nf] = (f32x4){bv, bv, bv, bv};
    }
    const int arow = w * 16 + col;
#pragma unroll
    for (int tt = 0; tt < 2; ++tt) {
        int k0 = tt * 32 + ko;
        bf16x8 ahi = *(const bf16x8*)&h_hi[arow][k0];
        bf16x8 alo = *(const bf16x8*)&h_lo[arow][k0];
#pragma unroll
        for (int nf = 0; nf < 4; ++nf) {
            bf16x8 bh = *(const bf16x8*)(w2h + (size_t)((tt * 4 + nf) * 64 + lane) * 8);
            bf16x8 bl = *(const bf16x8*)(w2l + (size_t)((tt * 4 + nf) * 64 + lane) * 8);
            out[nf] = __builtin_amdgcn_mfma_f32_16x16x32_bf16(ahi, bh, out[nf], 0, 0, 0);
            out[nf] = __builtin_amdgcn_mfma_f32_16x16x32_bf16(ahi, bl, out[nf], 0, 0, 0);
            out[nf] = __builtin_amdgcn_mfma_f32_16x16x32_bf16(alo, bh, out[nf], 0, 0, 0);
        }
    }

    // ---- epilogue: direct stores + transposed atomic scatter ----
    const int rbase = w * 16 + g * 4;
#pragma unroll
    for (int rg = 0; rg < 4; ++rg) {
        long row = base + rbase + rg;
        if (row < E) {
            int d = dst_idx[row];
            float* op = ea_out + row * 64;
            float* ap = agg + (long)d * 64;
#pragma unroll
            for (int nf = 0; nf < 4; ++nf) {
                op[nf * 16 + col] = out[nf][rg];
                atomicAdd(&ap[nf * 16 + col], out[nf][rg]);
            }
        }
    }
}

// ---------------------------------------------------------------------------
// Node kernel: direct A-fragment loads (x, agg rows are sequential), LDS only
// for the h transpose. Same wave decomposition, no atomics.
// ---------------------------------------------------------------------------
__global__ __launch_bounds__(256, 4) void gnn_node_mfma(
    const float* __restrict__ x_in,
    const float* __restrict__ aggp,
    float* __restrict__ x_out,
    const short* __restrict__ w1h, const short* __restrict__ w1l,
    const float* __restrict__ b1,
    const short* __restrict__ w2h, const short* __restrict__ w2l,
    const float* __restrict__ b2, int N)
{
    __shared__ __align__(16) short h_hi[64][HP];
    __shared__ __align__(16) short h_lo[64][HP];

    const int t    = threadIdx.x;
    const int lane = t & 63;
    const int w    = t >> 6;
    const int col  = lane & 15;
    const int g    = lane >> 4;
    const int ko   = g * 8;
    const long base = (long)blockIdx.x * 64;

    long nr = base + w * 16 + col;
    if (nr >= N) nr = N - 1;
    const float* px = x_in + nr * 64 + ko;
    const float* pa = aggp + nr * 64 + ko;

    float4 v0 = *(const float4*)(px);
    float4 v1 = *(const float4*)(px + 4);
    float4 v2 = *(const float4*)(px + 32);
    float4 v3 = *(const float4*)(px + 36);
    float4 v4 = *(const float4*)(pa);
    float4 v5 = *(const float4*)(pa + 4);
    float4 v6 = *(const float4*)(pa + 32);
    float4 v7 = *(const float4*)(pa + 36);

    f32x4 acc[4];
#pragma unroll
    for (int nf = 0; nf < 4; ++nf) {
        float bv = b1[nf * 16 + col];
        acc[nf] = (f32x4){bv, bv, bv, bv};
    }

#define QTR(m, A, B)                                                            \
    {                                                                           \
        bf16x8 ah, al;                                                          \
        cvt8(A, B, ah, al);                                                     \
        _Pragma("unroll")                                                       \
        for (int nf = 0; nf < 4; ++nf) {                                        \
            bf16x8 bh = *(const bf16x8*)(w1h + (size_t)(((m)*4+nf)*64+lane)*8); \
            bf16x8 bl = *(const bf16x8*)(w1l + (size_t)(((m)*4+nf)*64+lane)*8); \
            acc[nf] = __builtin_amdgcn_mfma_f32_16x16x32_bf16(ah, bh, acc[nf], 0, 0, 0); \
            acc[nf] = __builtin_amdgcn_mfma_f32_16x16x32_bf16(ah, bl, acc[nf], 0, 0, 0); \
            acc[nf] = __builtin_amdgcn_mfma_f32_16x16x32_bf16(al, bh, acc[nf], 0, 0, 0); \
        }                                                                       \
    }
    QTR(0, v0, v1)  QTR(1, v2, v3)   // x    (k 0..63)
    QTR(2, v4, v5)  QTR(3, v6, v7)   // agg  (k 64..127)
#undef QTR

#pragma unroll
    for (int nf = 0; nf < 4; ++nf)
#pragma unroll
        for (int rg = 0; rg < 4; ++rg) {
            int row = w * 16 + g * 4 + rg;
            short hh, hl;
            split_bf(silu_f(acc[nf][rg]), hh, hl);
            h_hi[row][nf * 16 + col] = hh;
            h_lo[row][nf * 16 + col] = hl;
        }

    f32x4 out[4];
#pragma unroll
    for (int nf = 0; nf < 4; ++nf) {
        float bv = b2[nf * 16 + col];
        out[nf] = (f32x4){bv, bv, bv, bv};
    }
    const int arow = w * 16 + col;
#pragma unroll
    for (int tt = 0; tt < 2; ++tt) {
        int k0 = tt * 32 + ko;
        bf16x8 ahi = *(const bf16x8*)&h_hi[arow][k0];
        bf16x8 alo = *(const bf16x8*)&h_lo[arow][k0];
#pragma unroll
        for (int nf = 0; nf < 4; ++nf) {
            bf16x8 bh = *(const bf16x8*)(w2h + (size_t)((tt * 4 + nf) * 64 + lane) * 8);
            bf16x8 bl = *(const bf16x8*)(w2l + (size_t)((tt * 4 + nf) * 64 + lane) * 8);
            out[nf] = __builtin_amdgcn_mfma_f32_16x16x32_bf16(ahi, bh, out[nf], 0, 0, 0);
            out[nf] = __builtin_amdgcn_mfma_f32_16x16x32_bf16(ahi, bl, out[nf], 0, 0, 0);
            out[nf] = __builtin_amdgcn_mfma_f32_16x16x32_bf16(alo, bh, out[nf], 0, 0, 0);
        }
    }

    const int rbase = w * 16 + g * 4;
#pragma unroll
    for (int rg = 0; rg < 4; ++rg) {
        long row = base + rbase + rg;
        if (row < N) {
            float* op = x_out + row * 64;
#pragma unroll
            for (int nf = 0; nf < 4; ++nf)
                op[nf * 16 + col] = out[nf][rg];
        }
    }
}

extern "C" void kernel_launch(void* const* d_in, const int* in_sizes, int n_in,
                              void* d_out, int out_size, void* d_ws, size_t ws_size,
                              hipStream_t stream) {
    const int H = 64;
    const int N = in_sizes[0] / H;   // 50000
    const int E = in_sizes[1] / H;   // 800000

    const float* x0  = (const float*)d_in[0];
    const float* ea0 = (const float*)d_in[1];
    const int*   ei  = (const int*)d_in[2];
    const float* ew1 = (const float*)d_in[3];
    const float* eb1 = (const float*)d_in[4];
    const float* ew2 = (const float*)d_in[5];
    const float* eb2 = (const float*)d_in[6];
    const float* nw1 = (const float*)d_in[7];
    const float* nb1 = (const float*)d_in[8];
    const float* nw2 = (const float*)d_in[9];
    const float* nb2 = (const float*)d_in[10];

    float* outX = (float*)d_out;                 // [N, H]
    float* outE = outX + (size_t)N * H;          // [E, H]
    float* agg  = (float*)d_ws;                  // [N, H] fp32
    short* wbase = (short*)((char*)d_ws + (size_t)N * H * sizeof(float));

    const int* srcI = ei;
    const int* dstI = ei + E;

    WPack pack;
    size_t off = 0;
    short* EH[2]; short* EL[2]; short* E2H[2]; short* E2L[2];
    short* NH[2]; short* NL[2]; short* N2H[2]; short* N2L[2];
    for (int l = 0; l < 2; ++l) {
        EH[l]  = wbase + off; off += 192 * 64;
        EL[l]  = wbase + off; off += 192 * 64;
        E2H[l] = wbase + off; off += 64 * 64;
        E2L[l] = wbase + off; off += 64 * 64;
        NH[l]  = wbase + off; off += 128 * 64;
        NL[l]  = wbase + off; off += 128 * 64;
        N2H[l] = wbase + off; off += 64 * 64;
        N2L[l] = wbase + off; off += 64 * 64;
        pack.d[l * 4 + 0] = {ew1 + (size_t)l * 192 * 64, EH[l],  EL[l],  192};
        pack.d[l * 4 + 1] = {ew2 + (size_t)l * 64 * 64,  E2H[l], E2L[l], 64};
        pack.d[l * 4 + 2] = {nw1 + (size_t)l * 128 * 64, NH[l],  NL[l],  128};
        pack.d[l * 4 + 3] = {nw2 + (size_t)l * 64 * 64,  N2H[l], N2L[l], 64};
    }
    conv_weights<<<dim3(48, 8), 256, 0, stream>>>(pack);

    const int egrid = (E + 63) / 64;
    const int ngrid = (N + 63) / 64;
    const size_t aggBytes = (size_t)N * H * sizeof(float);

    for (int l = 0; l < 2; ++l) {
        const float* xin  = (l == 0) ? x0  : outX;
        const float* eain = (l == 0) ? ea0 : outE;
        hipMemsetAsync(agg, 0, aggBytes, stream);
        gnn_edge_mfma<<<egrid, 256, 0, stream>>>(
            xin, eain, outE, srcI, dstI,
            EH[l], EL[l], eb1 + l * H,
            E2H[l], E2L[l], eb2 + l * H,
            agg, E);
        gnn_node_mfma<<<ngrid, 256, 0, stream>>>(
            xin, agg, outX,
            NH[l], NL[l], nb1 + l * H,
            N2H[l], N2L[l], nb2 + l * H,
            N);
    }
}